// Round 1
// baseline (26134.589 us; speedup 1.0000x reference)
//
#include <hip/hip_runtime.h>

// GeodesicStateBlock: GRU-style scan (B=16,S=2048,D=512) + LayerNorm.
// Key identity: deformed == states, so out = LN(states).
//
// Architecture:
//  - pack_kernel: pre-pack W_gate (1024x1024) and W_cand (1024x512) f32 -> f16
//    in exact MFMA B-fragment order: Wpk[tile(96)][kchunk(32)][lane(64)][8].
//    Tiles 0..63 = gates cols, 64..95 = cand cols. K=1024 = [x_t ; h].
//  - rec_kernel: persistent, 16 blocks x 256 thr. Block j owns gate-cols
//    [64j,64j+64) and cand-cols [32j,32j+32) for ALL 16 batches (M=16 = batch
//    dim of mfma_f32_16x16x32_f16). Per step: phase A computes gates, publishes
//    r*h / z; spin barrier; phase B computes cand, updates h, writes raw h to
//    d_out; barrier. 2 barriers/step via step-indexed counters (no reuse races).
//  - ln_kernel: in-place LayerNorm over d_out rows.

typedef _Float16 half8 __attribute__((ext_vector_type(8)));
typedef float floatx4 __attribute__((ext_vector_type(4)));

#define NBLK 16
#define TPB  256

// ws layout (bytes)
#define OFF_WPK   0ull                      // 96*32*64*8 f16 = 3,145,728 B
#define OFF_HBUF  3145728ull                // 16*512 f16 = 16 KB (zeroed: h0)
#define OFF_CNT   (3145728ull + 16384ull)   // 4096 u32 = 16 KB (zeroed)
#define OFF_RH    (3145728ull + 32768ull)   // 16 KB
#define OFF_Z     (3145728ull + 49152ull)   // 16 KB

__device__ __forceinline__ float sigmoid_f(float x) {
  return 1.f / (1.f + __expf(-x));
}
__device__ __forceinline__ float tanh_f(float x) {
  x = fminf(15.f, fmaxf(-15.f, x));
  float e = __expf(2.f * x);
  return (e - 1.f) / (e + 1.f);
}

__global__ void pack_kernel(const float* __restrict__ Wg,
                            const float* __restrict__ Wc,
                            _Float16* __restrict__ Wpk) {
  // unit = tile*32 + kchunk; 3072 units, 4 per block (one per wave)
  int unit = blockIdx.x * 4 + (threadIdx.x >> 6);
  int lane = threadIdx.x & 63;
  int tile = unit >> 5, chunk = unit & 31;
  // B-fragment: lane holds B[k = chunk*32 + (lane>>4)*8 + j][n = lane&15]
  int kb = chunk * 32 + ((lane >> 4) << 3);
  int n = lane & 15;
  half8 w;
  if (tile < 64) {
    int col = tile * 16 + n;  // gate col 0..1023
#pragma unroll
    for (int j = 0; j < 8; ++j) w[j] = (_Float16)Wg[(size_t)(kb + j) * 1024 + col];
  } else {
    int col = (tile - 64) * 16 + n;  // cand col 0..511
#pragma unroll
    for (int j = 0; j < 8; ++j) w[j] = (_Float16)Wc[(size_t)(kb + j) * 512 + col];
  }
  *(half8*)(Wpk + ((size_t)unit * 64 + lane) * 8) = w;
}

__device__ __forceinline__ void gbar(unsigned* __restrict__ cnt, int idx) {
  __threadfence();          // release: make this block's stores device-visible
  __syncthreads();
  if (threadIdx.x == 0) {
    __hip_atomic_fetch_add(&cnt[idx], 1u, __ATOMIC_RELEASE, __HIP_MEMORY_SCOPE_AGENT);
    while (__hip_atomic_load(&cnt[idx], __ATOMIC_RELAXED, __HIP_MEMORY_SCOPE_AGENT) <
           (unsigned)NBLK)
      __builtin_amdgcn_s_sleep(2);
  }
  __syncthreads();
  __threadfence();          // acquire: invalidate stale cached lines
}

__global__ __launch_bounds__(TPB) void rec_kernel(
    const float* __restrict__ points, const float* __restrict__ b_gate,
    const float* __restrict__ b_cand, const _Float16* __restrict__ Wpk,
    _Float16* __restrict__ h_buf, _Float16* __restrict__ rh_buf,
    _Float16* __restrict__ z_buf, unsigned* __restrict__ cnt,
    float* __restrict__ out) {
  // padded rows (520) break the 16-way LDS bank collision of b-row strides
  __shared__ _Float16 x_lds[16][520];
  __shared__ _Float16 h_lds[16][520];
  __shared__ _Float16 rh_lds[16][520];

  const int tid = threadIdx.x;
  const int wave = tid >> 6, lane = tid & 63;
  const int ln15 = lane & 15;   // A: batch row m / B: col n / D: col n
  const int q = lane >> 4;      // A/B: k-quad / D: row-quad
  const int j = blockIdx.x;

  const int sb = tid >> 4;            // staging: batch row 0..15
  const int sc = (tid & 15) * 32;     // staging: 32-col chunk

  for (int t = 0; t < 2048; ++t) {
    // ---- stage x_t (f32->f16) and h into LDS ----
    {
      const float* xp = points + ((size_t)sb * 2048 + t) * 512 + sc;
#pragma unroll
      for (int u = 0; u < 4; ++u) {
        float4 f0 = ((const float4*)xp)[u * 2];
        float4 f1 = ((const float4*)xp)[u * 2 + 1];
        half8 hv;
        hv[0] = (_Float16)f0.x; hv[1] = (_Float16)f0.y;
        hv[2] = (_Float16)f0.z; hv[3] = (_Float16)f0.w;
        hv[4] = (_Float16)f1.x; hv[5] = (_Float16)f1.y;
        hv[6] = (_Float16)f1.z; hv[7] = (_Float16)f1.w;
        *(half8*)&x_lds[sb][sc + u * 8] = hv;
      }
      const _Float16* hb = h_buf + sb * 512 + sc;
#pragma unroll
      for (int u = 0; u < 4; ++u)
        *(half8*)&h_lds[sb][sc + u * 8] = *(const half8*)(hb + u * 8);
    }
    __syncthreads();

    // ---- phase A: gates = [x;h] @ Wg + b_gate ----
    {
      const int Tg = j * 4 + wave;  // 0..63, col block [16Tg,16Tg+16)
      floatx4 acc = {0.f, 0.f, 0.f, 0.f};
#pragma unroll 4
      for (int kc = 0; kc < 32; ++kc) {
        const _Float16* asrc = (kc < 16) ? &x_lds[ln15][kc * 32 + q * 8]
                                         : &h_lds[ln15][(kc - 16) * 32 + q * 8];
        half8 av = *(const half8*)asrc;
        half8 bv = *(const half8*)(Wpk + (((size_t)Tg * 32 + kc) * 64 + lane) * 8);
        acc = __builtin_amdgcn_mfma_f32_16x16x32_f16(av, bv, acc, 0, 0, 0);
      }
      const int col = Tg * 16 + ln15;
      const float bias = b_gate[col];
#pragma unroll
      for (int i = 0; i < 4; ++i) {
        int b = q * 4 + i;  // D: row = (lane>>4)*4 + reg = batch
        float s = sigmoid_f(acc[i] + bias);
        if (Tg < 32) {  // r-cols: publish r*h
          float hv = (float)h_lds[b][col];
          rh_buf[b * 512 + col] = (_Float16)(s * hv);
        } else {        // z-cols: publish z
          z_buf[b * 512 + (col - 512)] = (_Float16)s;
        }
      }
    }
    gbar(cnt, 2 * t);

    // ---- stage full r*h ----
    {
      const _Float16* rb = rh_buf + sb * 512 + sc;
#pragma unroll
      for (int u = 0; u < 4; ++u)
        *(half8*)&rh_lds[sb][sc + u * 8] = *(const half8*)(rb + u * 8);
    }
    __syncthreads();

    // ---- phase B: cand = tanh([x; r*h] @ Wc + b_cand); h update; output ----
    if (wave < 2) {
      const int Tc = j * 2 + wave;  // 0..31, cand cols [16Tc,16Tc+16)
      floatx4 acc = {0.f, 0.f, 0.f, 0.f};
#pragma unroll 4
      for (int kc = 0; kc < 32; ++kc) {
        const _Float16* asrc = (kc < 16) ? &x_lds[ln15][kc * 32 + q * 8]
                                         : &rh_lds[ln15][(kc - 16) * 32 + q * 8];
        half8 av = *(const half8*)asrc;
        half8 bv =
            *(const half8*)(Wpk + (((size_t)(64 + Tc) * 32 + kc) * 64 + lane) * 8);
        acc = __builtin_amdgcn_mfma_f32_16x16x32_f16(av, bv, acc, 0, 0, 0);
      }
      const int c = Tc * 16 + ln15;
      const float bias = b_cand[c];
#pragma unroll
      for (int i = 0; i < 4; ++i) {
        int b = q * 4 + i;
        float cv = tanh_f(acc[i] + bias);
        float z = (float)z_buf[b * 512 + c];
        float ho = (float)h_lds[b][c];
        float hn = ho + z * (cv - ho);
        h_buf[b * 512 + c] = (_Float16)hn;
        out[((size_t)b * 2048 + t) * 512 + c] = hn;  // raw state; LN later
      }
    }
    gbar(cnt, 2 * t + 1);
  }
}

__global__ void ln_kernel(float* __restrict__ out, const float* __restrict__ gamma,
                          const float* __restrict__ beta) {
  int gw = (blockIdx.x * blockDim.x + threadIdx.x) >> 6;
  int lane = threadIdx.x & 63;
  int nw = (gridDim.x * blockDim.x) >> 6;
  float4 ga = ((const float4*)(gamma + lane * 8))[0];
  float4 gb = ((const float4*)(gamma + lane * 8))[1];
  float4 ba = ((const float4*)(beta + lane * 8))[0];
  float4 bb = ((const float4*)(beta + lane * 8))[1];
  for (int r = gw; r < 16 * 2048; r += nw) {
    float* p = out + (size_t)r * 512 + lane * 8;
    float4 v0 = ((float4*)p)[0], v1 = ((float4*)p)[1];
    float s = v0.x + v0.y + v0.z + v0.w + v1.x + v1.y + v1.z + v1.w;
    float sq = v0.x * v0.x + v0.y * v0.y + v0.z * v0.z + v0.w * v0.w +
               v1.x * v1.x + v1.y * v1.y + v1.z * v1.z + v1.w * v1.w;
#pragma unroll
    for (int off = 32; off > 0; off >>= 1) {
      s += __shfl_xor(s, off);
      sq += __shfl_xor(sq, off);
    }
    float mean = s * (1.f / 512.f);
    float var = sq * (1.f / 512.f) - mean * mean;
    float rstd = rsqrtf(var + 1e-5f);
    v0.x = (v0.x - mean) * rstd * ga.x + ba.x;
    v0.y = (v0.y - mean) * rstd * ga.y + ba.y;
    v0.z = (v0.z - mean) * rstd * ga.z + ba.z;
    v0.w = (v0.w - mean) * rstd * ga.w + ba.w;
    v1.x = (v1.x - mean) * rstd * gb.x + bb.x;
    v1.y = (v1.y - mean) * rstd * gb.y + bb.y;
    v1.z = (v1.z - mean) * rstd * gb.z + bb.z;
    v1.w = (v1.w - mean) * rstd * gb.w + bb.w;
    ((float4*)p)[0] = v0;
    ((float4*)p)[1] = v1;
  }
}

extern "C" void kernel_launch(void* const* d_in, const int* in_sizes, int n_in,
                              void* d_out, int out_size, void* d_ws, size_t ws_size,
                              hipStream_t stream) {
  const float* points = (const float*)d_in[0];
  const float* W_gate = (const float*)d_in[1];
  const float* b_gate = (const float*)d_in[2];
  const float* W_cand = (const float*)d_in[3];
  const float* b_cand = (const float*)d_in[4];
  const float* gamma = (const float*)d_in[5];
  const float* beta = (const float*)d_in[6];
  char* ws = (char*)d_ws;
  _Float16* Wpk = (_Float16*)(ws + OFF_WPK);
  _Float16* h_buf = (_Float16*)(ws + OFF_HBUF);
  unsigned* cnt = (unsigned*)(ws + OFF_CNT);
  _Float16* rh_buf = (_Float16*)(ws + OFF_RH);
  _Float16* z_buf = (_Float16*)(ws + OFF_Z);
  float* out = (float*)d_out;

  // zero h0 + barrier counters (ws is 0xAA-poisoned before every launch)
  hipMemsetAsync(ws + OFF_HBUF, 0, 32768, stream);
  pack_kernel<<<768, 256, 0, stream>>>(W_gate, W_cand, Wpk);
  rec_kernel<<<NBLK, TPB, 0, stream>>>(points, b_gate, b_cand, Wpk, h_buf, rh_buf,
                                       z_buf, cnt, out);
  ln_kernel<<<512, 256, 0, stream>>>(out, gamma, beta);
}

// Round 3
// 13323.924 us; speedup vs baseline: 1.9615x; 1.9615x over previous
//
#include <hip/hip_runtime.h>

// GeodesicStateBlock: GRU-style scan (B=16,S=2048,D=512) + LayerNorm.
// Identity: deformed = points + (states - points) = states, so out = LN(states).
//
// Round-3 structure:
//  - pack_kernel: W_gate/W_cand f32 -> f16 in MFMA B-frag order, split into
//    h-part (rows 512..1023 -> Whpk) and x-part (rows 0..511 -> Wxpk).
//    Tile = 16 kc x 64 lanes x 8 f16 = 8192 f16 (16 KB). 96 tiles per set.
//  - xgemm_kernel: XGT[t][96][c16][b16] f16 = points @ W_x + bias, all steps.
//  - rec_kernel: persistent 16 blocks x 256 thr, NO LDS staging.
//    Weights live in VGPRs (wA[16], wB[16] half8 frags per wave).
//    A-fragments of h / r*h are loaded straight from global with coherent
//    (sc0 sc1) dwordx4 loads; h[b][colA] is carried in registers (hreg[4]).
//    Cross-block exchange: sc0 sc1 stores -> vmcnt(0) -> relaxed agent atomic
//    counter barrier (step-indexed). No __threadfence => no buffer_wbl2/inv,
//    L2 stays warm; h/rh/cnt traffic is LLC-coherent by cache bypass.
//  - ln_kernel: in-place LayerNorm on d_out.

typedef _Float16 half8 __attribute__((ext_vector_type(8)));
typedef _Float16 half4 __attribute__((ext_vector_type(4)));
typedef float floatx4 __attribute__((ext_vector_type(4)));
typedef int int4v __attribute__((ext_vector_type(4)));

#define NBLK 16
#define TPB 256
#define S_LEN 2048

// ws layout (bytes)
#define SZ_WPK (96ull * 16 * 64 * 8 * 2)  // 1,572,864 (96 tiles x 16 KB)
#define OFF_WHPK 0ull
#define OFF_WXPK (OFF_WHPK + SZ_WPK)
#define OFF_HBUF (OFF_WXPK + SZ_WPK)   // 16 KB (zeroed: h0)
#define OFF_CNT (OFF_HBUF + 16384ull)  // 16 KB (zeroed: barrier counters)
#define OFF_RH (OFF_CNT + 16384ull)    // 16 KB
#define OFF_XGT (OFF_RH + 16384ull)    // 2048*96*256*2 = 100,663,296 B

__device__ __forceinline__ float sigmoid_f(float x) {
  return 1.f / (1.f + __expf(-x));
}
__device__ __forceinline__ float tanh_f(float x) {
  x = fminf(15.f, fmaxf(-15.f, x));
  float e = __expf(2.f * x);
  return (e - 1.f) / (e + 1.f);
}

// ---- coherent (LLC-level) memory ops: bypass per-XCD L1/L2 ----
// Load 16 A-fragments (16B each, 64B apart) + drain, in ONE asm block so the
// compiler can never schedule a use before the waitcnt.
__device__ __forceinline__ void ldfrag_cg(const _Float16* p, int4v (&f)[16]) {
  asm volatile(
      "global_load_dwordx4 %0,  %16, off sc0 sc1\n\t"
      "global_load_dwordx4 %1,  %16, off offset:64 sc0 sc1\n\t"
      "global_load_dwordx4 %2,  %16, off offset:128 sc0 sc1\n\t"
      "global_load_dwordx4 %3,  %16, off offset:192 sc0 sc1\n\t"
      "global_load_dwordx4 %4,  %16, off offset:256 sc0 sc1\n\t"
      "global_load_dwordx4 %5,  %16, off offset:320 sc0 sc1\n\t"
      "global_load_dwordx4 %6,  %16, off offset:384 sc0 sc1\n\t"
      "global_load_dwordx4 %7,  %16, off offset:448 sc0 sc1\n\t"
      "global_load_dwordx4 %8,  %16, off offset:512 sc0 sc1\n\t"
      "global_load_dwordx4 %9,  %16, off offset:576 sc0 sc1\n\t"
      "global_load_dwordx4 %10, %16, off offset:640 sc0 sc1\n\t"
      "global_load_dwordx4 %11, %16, off offset:704 sc0 sc1\n\t"
      "global_load_dwordx4 %12, %16, off offset:768 sc0 sc1\n\t"
      "global_load_dwordx4 %13, %16, off offset:832 sc0 sc1\n\t"
      "global_load_dwordx4 %14, %16, off offset:896 sc0 sc1\n\t"
      "global_load_dwordx4 %15, %16, off offset:960 sc0 sc1\n\t"
      "s_waitcnt vmcnt(0)"
      : "=&v"(f[0]), "=&v"(f[1]), "=&v"(f[2]), "=&v"(f[3]), "=&v"(f[4]),
        "=&v"(f[5]), "=&v"(f[6]), "=&v"(f[7]), "=&v"(f[8]), "=&v"(f[9]),
        "=&v"(f[10]), "=&v"(f[11]), "=&v"(f[12]), "=&v"(f[13]), "=&v"(f[14]),
        "=&v"(f[15])
      : "v"(p)
      : "memory");
}
__device__ __forceinline__ void st_cg_u16(_Float16* p, _Float16 v) {
  unsigned u = (unsigned)__builtin_bit_cast(unsigned short, v);
  asm volatile("global_store_short %0, %1, off sc0 sc1" ::"v"(p), "v"(u)
               : "memory");
}
__device__ __forceinline__ void vwait() {
  asm volatile("s_waitcnt vmcnt(0)" ::: "memory");
}

// step-indexed spin barrier; callers drain vmcnt (vwait) before arriving.
__device__ __forceinline__ void gbar(unsigned* __restrict__ cnt, int idx) {
  __syncthreads();
  if (threadIdx.x == 0) {
    __hip_atomic_fetch_add(&cnt[idx], 1u, __ATOMIC_RELAXED,
                           __HIP_MEMORY_SCOPE_AGENT);
    while (__hip_atomic_load(&cnt[idx], __ATOMIC_RELAXED,
                             __HIP_MEMORY_SCOPE_AGENT) < (unsigned)NBLK) {
    }
  }
  __syncthreads();
}

// ---- pack weights into MFMA B-fragment order ----
// Whpk/Wxpk: [96 tiles][16 kc][64 lanes][8 f16]; tiles 0..63 gate, 64..95 cand.
// B-frag: lane holds B[k = kc*32 + (lane>>4)*8 + jj][n = lane&15].
__global__ void pack_kernel(const float* __restrict__ Wg,
                            const float* __restrict__ Wc,
                            _Float16* __restrict__ Whpk,
                            _Float16* __restrict__ Wxpk) {
  int unit = blockIdx.x * 4 + (threadIdx.x >> 6);  // 0..3071
  int lane = threadIdx.x & 63;
  int set = (unit >= 1536) ? 1 : 0;  // 0: h-part (rows 512+), 1: x-part
  int rem = unit - set * 1536;
  int tile = rem >> 4, kc = rem & 15;
  int kb = kc * 32 + ((lane >> 4) << 3);
  int n = lane & 15;
  int row0 = set ? 0 : 512;
  half8 w;
  if (tile < 64) {
    int col = tile * 16 + n;
#pragma unroll
    for (int jj = 0; jj < 8; ++jj)
      w[jj] = (_Float16)Wg[(size_t)(row0 + kb + jj) * 1024 + col];
  } else {
    int col = (tile - 64) * 16 + n;
#pragma unroll
    for (int jj = 0; jj < 8; ++jj)
      w[jj] = (_Float16)Wc[(size_t)(row0 + kb + jj) * 512 + col];
  }
  _Float16* dst = set ? Wxpk : Whpk;
  *(half8*)(dst + ((size_t)rem * 64 + lane) * 8) = w;
}

// ---- XGT = points @ W_x + bias, all steps; layout [t][tile][c16][b16] ----
__global__ __launch_bounds__(TPB) void xgemm_kernel(
    const float* __restrict__ points, const float* __restrict__ b_gate,
    const float* __restrict__ b_cand, const _Float16* __restrict__ Wxpk,
    _Float16* __restrict__ xgt) {
  __shared__ _Float16 x_lds[16][520];
  const int tid = threadIdx.x;
  const int wave = tid >> 6, lane = tid & 63;
  const int ln15 = lane & 15, q = lane >> 4;
  const int t = blockIdx.x;
  const int m = tid & 15, ch = tid >> 4;

  // stage x_t (f32 -> f16)
  const float* xp = points + ((size_t)m * S_LEN + t) * 512 + ch * 32;
#pragma unroll
  for (int u = 0; u < 4; ++u) {
    float4 f0 = ((const float4*)xp)[2 * u];
    float4 f1 = ((const float4*)xp)[2 * u + 1];
    half8 hv;
    hv[0] = (_Float16)f0.x; hv[1] = (_Float16)f0.y;
    hv[2] = (_Float16)f0.z; hv[3] = (_Float16)f0.w;
    hv[4] = (_Float16)f1.x; hv[5] = (_Float16)f1.y;
    hv[6] = (_Float16)f1.z; hv[7] = (_Float16)f1.w;
    *(half8*)&x_lds[m][ch * 32 + u * 8] = hv;
  }
  __syncthreads();

  for (int tile = wave; tile < 96; tile += 4) {
    const _Float16* W = Wxpk + (size_t)tile * 8192;
    floatx4 a0 = {0.f, 0.f, 0.f, 0.f}, a1 = {0.f, 0.f, 0.f, 0.f};
#pragma unroll
    for (int kc = 0; kc < 16; kc += 2) {
      a0 = __builtin_amdgcn_mfma_f32_16x16x32_f16(
          *(const half8*)&x_lds[ln15][kc * 32 + q * 8],
          *(const half8*)(W + ((size_t)kc * 64 + lane) * 8), a0, 0, 0, 0);
      a1 = __builtin_amdgcn_mfma_f32_16x16x32_f16(
          *(const half8*)&x_lds[ln15][(kc + 1) * 32 + q * 8],
          *(const half8*)(W + ((size_t)(kc + 1) * 64 + lane) * 8), a1, 0, 0, 0);
    }
    float bias = (tile < 64) ? b_gate[tile * 16 + ln15]
                             : b_cand[(tile - 64) * 16 + ln15];
    half4 o;
#pragma unroll
    for (int i = 0; i < 4; ++i) o[i] = (_Float16)(a0[i] + a1[i] + bias);
    *(half4*)(xgt + (((size_t)t * 96 + tile) * 16 + ln15) * 16 + q * 4) = o;
  }
}

// ---- serial recurrence: 16 persistent blocks, register-resident weights ----
__global__ __launch_bounds__(TPB, 1) void rec_kernel(
    const _Float16* __restrict__ Whpk, const _Float16* __restrict__ xgt,
    _Float16* __restrict__ h_buf, _Float16* __restrict__ rh_buf,
    unsigned* __restrict__ cnt, float* __restrict__ out) {
  __shared__ float z_lds[16][36];

  const int tid = threadIdx.x;
  const int wave = tid >> 6, lane = tid & 63;
  const int ln15 = lane & 15, q = lane >> 4;
  const int j = blockIdx.x;

  // wave -> tiles: waves 0,1 gate-r tiles 2j,2j+1 (cols 32j..32j+31) + cand
  // tiles 64+2j,65+2j; waves 2,3 gate-z tiles 32+2j,33+2j.
  const int twA = (wave < 2) ? (2 * j + wave) : (32 + 2 * j + (wave - 2));
  const int twB = 64 + 2 * j + (wave & 1);
  const int colA = 32 * j + 16 * (wave & 1) + ln15;

  // weights -> registers (tile stride 8192 f16; kc stride 512 f16)
  half8 wA[16], wB[16];
  {
    const _Float16* sA = Whpk + (size_t)twA * 8192 + lane * 8;
#pragma unroll
    for (int kc = 0; kc < 16; ++kc) wA[kc] = *(const half8*)(sA + kc * 512);
  }
  if (wave < 2) {
    const _Float16* sB = Whpk + (size_t)twB * 8192 + lane * 8;
#pragma unroll
    for (int kc = 0; kc < 16; ++kc) wB[kc] = *(const half8*)(sB + kc * 512);
  }

  const _Float16* hA_base = h_buf + ln15 * 512 + q * 8;
  const _Float16* rhA_base = rh_buf + ln15 * 512 + q * 8;
  _Float16* rh_st = rh_buf + (q * 4) * 512 + colA;  // + i*512
  _Float16* h_st = h_buf + (q * 4) * 512 + colA;    // + i*512

  float hreg[4] = {0.f, 0.f, 0.f, 0.f};  // h[q*4+i][colA] (waves 0-1)

  for (int t = 0; t < S_LEN; ++t) {
    half4 xga =
        *(const half4*)(xgt + (((size_t)t * 96 + twA) * 16 + ln15) * 16 + q * 4);

    // phase A: gates = h @ Wg_h + xg
    int4v hf[16];
    ldfrag_cg(hA_base, hf);
    floatx4 a0 = {0.f, 0.f, 0.f, 0.f}, a1 = {0.f, 0.f, 0.f, 0.f};
#pragma unroll
    for (int kc = 0; kc < 16; kc += 2) {
      a0 = __builtin_amdgcn_mfma_f32_16x16x32_f16(
          __builtin_bit_cast(half8, hf[kc]), wA[kc], a0, 0, 0, 0);
      a1 = __builtin_amdgcn_mfma_f32_16x16x32_f16(
          __builtin_bit_cast(half8, hf[kc + 1]), wA[kc + 1], a1, 0, 0, 0);
    }
    if (wave < 2) {  // r-cols: publish r*h (coherent)
#pragma unroll
      for (int i = 0; i < 4; ++i) {
        float r = sigmoid_f(a0[i] + a1[i] + (float)xga[i]);
        st_cg_u16(rh_st + i * 512, (_Float16)(r * hreg[i]));
      }
      vwait();
    } else {  // z-cols: stash in LDS (consumed by waves 0-1 after the barrier)
#pragma unroll
      for (int i = 0; i < 4; ++i)
        z_lds[q * 4 + i][16 * (wave - 2) + ln15] =
            sigmoid_f(a0[i] + a1[i] + (float)xga[i]);
    }
    gbar(cnt, 2 * t);

    // phase B: cand = tanh(rh @ Wc_h + xc); h update; raw-state output
    if (wave < 2) {
      half4 xcb = *(const half4*)(xgt + (((size_t)t * 96 + twB) * 16 + ln15) * 16 +
                                  q * 4);
      int4v rf[16];
      ldfrag_cg(rhA_base, rf);
      floatx4 b0 = {0.f, 0.f, 0.f, 0.f}, b1 = {0.f, 0.f, 0.f, 0.f};
#pragma unroll
      for (int kc = 0; kc < 16; kc += 2) {
        b0 = __builtin_amdgcn_mfma_f32_16x16x32_f16(
            __builtin_bit_cast(half8, rf[kc]), wB[kc], b0, 0, 0, 0);
        b1 = __builtin_amdgcn_mfma_f32_16x16x32_f16(
            __builtin_bit_cast(half8, rf[kc + 1]), wB[kc + 1], b1, 0, 0, 0);
      }
#pragma unroll
      for (int i = 0; i < 4; ++i) {
        float cv = tanh_f(b0[i] + b1[i] + (float)xcb[i]);
        float zz = z_lds[q * 4 + i][16 * wave + ln15];
        float hn = hreg[i] + zz * (cv - hreg[i]);
        _Float16 hh = (_Float16)hn;
        hreg[i] = (float)hh;  // keep register copy == published f16 copy
        st_cg_u16(h_st + i * 512, hh);
        out[((size_t)(q * 4 + i) * S_LEN + t) * 512 + colA] = hn;
      }
      vwait();
    }
    gbar(cnt, 2 * t + 1);
  }
}

__global__ void ln_kernel(float* __restrict__ out, const float* __restrict__ gamma,
                          const float* __restrict__ beta) {
  int gw = (blockIdx.x * blockDim.x + threadIdx.x) >> 6;
  int lane = threadIdx.x & 63;
  int nw = (gridDim.x * blockDim.x) >> 6;
  float4 ga = ((const float4*)(gamma + lane * 8))[0];
  float4 gb = ((const float4*)(gamma + lane * 8))[1];
  float4 ba = ((const float4*)(beta + lane * 8))[0];
  float4 bb = ((const float4*)(beta + lane * 8))[1];
  for (int r = gw; r < 16 * S_LEN; r += nw) {
    float* p = out + (size_t)r * 512 + lane * 8;
    float4 v0 = ((float4*)p)[0], v1 = ((float4*)p)[1];
    float s = v0.x + v0.y + v0.z + v0.w + v1.x + v1.y + v1.z + v1.w;
    float sq = v0.x * v0.x + v0.y * v0.y + v0.z * v0.z + v0.w * v0.w +
               v1.x * v1.x + v1.y * v1.y + v1.z * v1.z + v1.w * v1.w;
#pragma unroll
    for (int off = 32; off > 0; off >>= 1) {
      s += __shfl_xor(s, off);
      sq += __shfl_xor(sq, off);
    }
    float mean = s * (1.f / 512.f);
    float var = sq * (1.f / 512.f) - mean * mean;
    float rstd = rsqrtf(var + 1e-5f);
    v0.x = (v0.x - mean) * rstd * ga.x + ba.x;
    v0.y = (v0.y - mean) * rstd * ga.y + ba.y;
    v0.z = (v0.z - mean) * rstd * ga.z + ba.z;
    v0.w = (v0.w - mean) * rstd * ga.w + ba.w;
    v1.x = (v1.x - mean) * rstd * gb.x + bb.x;
    v1.y = (v1.y - mean) * rstd * gb.y + bb.y;
    v1.z = (v1.z - mean) * rstd * gb.z + bb.z;
    v1.w = (v1.w - mean) * rstd * gb.w + bb.w;
    ((float4*)p)[0] = v0;
    ((float4*)p)[1] = v1;
  }
}

extern "C" void kernel_launch(void* const* d_in, const int* in_sizes, int n_in,
                              void* d_out, int out_size, void* d_ws,
                              size_t ws_size, hipStream_t stream) {
  const float* points = (const float*)d_in[0];
  const float* W_gate = (const float*)d_in[1];
  const float* b_gate = (const float*)d_in[2];
  const float* W_cand = (const float*)d_in[3];
  const float* b_cand = (const float*)d_in[4];
  const float* gamma = (const float*)d_in[5];
  const float* beta = (const float*)d_in[6];
  char* ws = (char*)d_ws;
  _Float16* Whpk = (_Float16*)(ws + OFF_WHPK);
  _Float16* Wxpk = (_Float16*)(ws + OFF_WXPK);
  _Float16* h_buf = (_Float16*)(ws + OFF_HBUF);
  unsigned* cnt = (unsigned*)(ws + OFF_CNT);
  _Float16* rh_buf = (_Float16*)(ws + OFF_RH);
  _Float16* xgt = (_Float16*)(ws + OFF_XGT);
  float* out = (float*)d_out;

  // zero h0 + barrier counters (ws is re-poisoned before every timed launch)
  hipMemsetAsync(ws + OFF_HBUF, 0, 32768, stream);
  pack_kernel<<<768, 256, 0, stream>>>(W_gate, W_cand, Whpk, Wxpk);
  xgemm_kernel<<<S_LEN, TPB, 0, stream>>>(points, b_gate, b_cand, Wxpk, xgt);
  rec_kernel<<<NBLK, TPB, 0, stream>>>(Whpk, xgt, h_buf, rh_buf, cnt, out);
  ln_kernel<<<512, 256, 0, stream>>>(out, gamma, beta);
}